// Round 9
// baseline (344.688 us; speedup 1.0000x reference)
//
#include <hip/hip_runtime.h>

#define L_NODES 100000
#define NFEAT   256
#define JDIM    128

typedef __bf16 bf16x8 __attribute__((ext_vector_type(8)));
typedef __bf16 bf16x4 __attribute__((ext_vector_type(4)));
typedef float  floatx4 __attribute__((ext_vector_type(4)));

// ---------------------------------------------------------------------------
// Prep (into d_ws weight region — NOT d_out, which raced in R7):
//   WtH[n][k]  = bf16(W_h1[k][n])        n,k in [0,128)x[0,256)
//   WtGu[n][k] = bf16(W_g1[k][n])        n,k in [0,128)x[0,256)
//   WtGb[n][k] = bf16(W_g1[128+k][n])    n,k in [0,128)x[0,128)
// ---------------------------------------------------------------------------
__global__ __launch_bounds__(256) void k_prep(
    const float* __restrict__ Wh, const float* __restrict__ Wg,
    __bf16* __restrict__ WtH, __bf16* __restrict__ WtGu,
    __bf16* __restrict__ WtGb)
{
    int i = blockIdx.x * 256 + threadIdx.x;   // 32768
    int n = i >> 8, k = i & 255;
    WtH[i]  = (__bf16)Wh[k * JDIM + n];
    WtGu[i] = (__bf16)Wg[k * JDIM + n];
    if (i < 16384) {
        int n2 = i >> 7, k2 = i & 127;
        WtGb[i] = (__bf16)Wg[(128 + k2) * JDIM + n2];
    }
}

// ---------------------------------------------------------------------------
// Kernel 1 (fused, MFMA), 64-row blocks (1563 blocks for overlap; R8's
// 128-row version had only 3.05 blocks/CU of work -> 9% occupancy):
//   phase 1: H = relu(X @ W_h1 + b) into LDS      (K=256, one staging pass)
//   phase 2a: U = H @ Wg[0:128,:]  -> global
//   phase 2b: V = H @ Wg[128:,:]   -> global      (sequential, reuses acc[8])
// Wave = 1 m-tile (16 rows) x 8 n-tiles throughout.
// ---------------------------------------------------------------------------
__global__ __launch_bounds__(256) void k_h1uv(
    const float* __restrict__ X, const __bf16* __restrict__ WtH,
    const __bf16* __restrict__ WtGu, const float* __restrict__ b,
    __bf16* __restrict__ U, __bf16* __restrict__ V)
{
    __shared__ __bf16 As[64 * 264];          // 33792 B raw
    __bf16* Hs = As;                         // [64][136] after phase 1
    __bf16* Os = As + 64 * 136;              // [64][128] staging for U/V

    const int tid  = threadIdx.x;
    const int row0 = blockIdx.x * 64;
    const int wave = tid >> 6, lane = tid & 63;
    const int lm = lane & 15, lq = lane >> 4;

    // ---- stage X tile: 64 rows x 256 cols fp32 -> bf16 (stride 264) ----
    #pragma unroll
    for (int it = 0; it < 16; ++it) {
        int f4  = it * 256 + tid;            // 4096 float4 chunks
        int row = f4 >> 6;                   // 64 float4 per row
        int c4  = f4 & 63;
        int grow = row0 + row; if (grow >= L_NODES) grow = L_NODES - 1;
        float4 v = *(const float4*)(X + (size_t)grow * NFEAT + c4 * 4);
        bf16x4 o; o[0]=(__bf16)v.x; o[1]=(__bf16)v.y; o[2]=(__bf16)v.z; o[3]=(__bf16)v.w;
        *(bf16x4*)&As[row * 264 + c4 * 4] = o;
    }
    __syncthreads();

    // ---- phase 1: H m-tile per wave, 8 n-tiles, K=256 ----
    floatx4 acc[8] = {};
    {
        const __bf16* bbase = WtH + (size_t)lm * 256 + lq * 8;
        bf16x8 bc[8], bn[8];
        #pragma unroll
        for (int nt = 0; nt < 8; ++nt)
            bc[nt] = *(const bf16x8*)(bbase + (size_t)nt * 16 * 256);
        #pragma unroll
        for (int ks = 0; ks < 8; ++ks) {
            if (ks < 7)
                #pragma unroll
                for (int nt = 0; nt < 8; ++nt)
                    bn[nt] = *(const bf16x8*)(bbase + (size_t)nt * 16 * 256 + (ks + 1) * 32);
            bf16x8 af = *(const bf16x8*)&As[(wave * 16 + lm) * 264 + ks * 32 + lq * 8];
            #pragma unroll
            for (int nt = 0; nt < 8; ++nt)
                acc[nt] = __builtin_amdgcn_mfma_f32_16x16x32_bf16(af, bc[nt], acc[nt], 0, 0, 0);
            #pragma unroll
            for (int nt = 0; nt < 8; ++nt) bc[nt] = bn[nt];
        }
    }
    __syncthreads();   // all X reads done; safe to overwrite with Hs

    // H (bias+relu, bf16) -> Hs[64][136]
    #pragma unroll
    for (int nt = 0; nt < 8; ++nt) {
        int col = nt * 16 + lm;
        float bias = b[col];
        #pragma unroll
        for (int p = 0; p < 4; ++p)
            Hs[(wave * 16 + lq * 4 + p) * 136 + col] =
                (__bf16)fmaxf(acc[nt][p] + bias, 0.f);
    }
    __syncthreads();

    // ---- phase 2a: U = H @ Wg_top  (K=128) ----
    #pragma unroll
    for (int nt = 0; nt < 8; ++nt) acc[nt] = (floatx4){};
    #pragma unroll
    for (int ks = 0; ks < 4; ++ks) {
        bf16x8 af = *(const bf16x8*)&Hs[(wave * 16 + lm) * 136 + ks * 32 + lq * 8];
        #pragma unroll
        for (int nt = 0; nt < 8; ++nt) {
            bf16x8 bc = *(const bf16x8*)(WtGu + (size_t)(nt * 16 + lm) * 256 + ks * 32 + lq * 8);
            acc[nt] = __builtin_amdgcn_mfma_f32_16x16x32_bf16(af, bc, acc[nt], 0, 0, 0);
        }
    }
    #pragma unroll
    for (int nt = 0; nt < 8; ++nt) {
        int col = nt * 16 + lm;
        #pragma unroll
        for (int p = 0; p < 4; ++p)
            Os[(wave * 16 + lq * 4 + p) * 128 + col] = (__bf16)acc[nt][p];
    }
    __syncthreads();
    #pragma unroll
    for (int it = 0; it < 4; ++it) {
        int fid = it * 256 + tid;
        int row = fid >> 4, fr = fid & 15;
        int grow = row0 + row;
        if (grow < L_NODES)
            *(bf16x8*)(U + (size_t)grow * JDIM + fr * 8) = *(bf16x8*)&Os[row * 128 + fr * 8];
    }
    __syncthreads();   // U store reads done; Os reusable

    // ---- phase 2b: V = H @ Wg_bot  (K=128, B cols 128..255 of WtGu rows) ----
    #pragma unroll
    for (int nt = 0; nt < 8; ++nt) acc[nt] = (floatx4){};
    #pragma unroll
    for (int ks = 0; ks < 4; ++ks) {
        bf16x8 af = *(const bf16x8*)&Hs[(wave * 16 + lm) * 136 + ks * 32 + lq * 8];
        #pragma unroll
        for (int nt = 0; nt < 8; ++nt) {
            bf16x8 bc = *(const bf16x8*)(WtGu + (size_t)(nt * 16 + lm) * 256 + 128 + ks * 32 + lq * 8);
            acc[nt] = __builtin_amdgcn_mfma_f32_16x16x32_bf16(af, bc, acc[nt], 0, 0, 0);
        }
    }
    #pragma unroll
    for (int nt = 0; nt < 8; ++nt) {
        int col = nt * 16 + lm;
        #pragma unroll
        for (int p = 0; p < 4; ++p)
            Os[(wave * 16 + lq * 4 + p) * 128 + col] = (__bf16)acc[nt][p];
    }
    __syncthreads();
    #pragma unroll
    for (int it = 0; it < 4; ++it) {
        int fid = it * 256 + tid;
        int row = fid >> 4, fr = fid & 15;
        int grow = row0 + row;
        if (grow < L_NODES)
            *(bf16x8*)(V + (size_t)grow * JDIM + fr * 8) = *(bf16x8*)&Os[row * 128 + fr * 8];
    }
}

// ---------------------------------------------------------------------------
// Kernel 2 (gather-add): E1b[i] = bf16(relu(mean_s relu(U[idx0]+V[idx1]+b)))
// R5-proven config. Random-BW bound (~6.6 TB/s delivered) — floor ~61 us.
// ---------------------------------------------------------------------------
__global__ __launch_bounds__(256) void k_gather(
    const __bf16* __restrict__ U, const __bf16* __restrict__ V,
    const float* __restrict__ b,
    const int* __restrict__ idx0, const int* __restrict__ idx1,
    __bf16* __restrict__ E1b)
{
    __shared__ int s0[8][16], s1[8][16];

    const int tid = threadIdx.x;
    const int i0  = blockIdx.x * 16;

    if (tid < 128) {
        int s = tid >> 4, il = tid & 15;
        s0[s][il] = idx0[(size_t)s * L_NODES + i0 + il];
    } else {
        int t = tid - 128, s = t >> 4, il = t & 15;
        s1[s][il] = idx1[(size_t)s * L_NODES + i0 + il];
    }
    __syncthreads();

    const int il = tid >> 4;
    const int c0 = (tid & 15) * 8;

    float bias[8];
    *(float4*)&bias[0] = *(const float4*)(b + c0);
    *(float4*)&bias[4] = *(const float4*)(b + c0 + 4);

    float acc[8] = {};
    #pragma unroll
    for (int s = 0; s < 8; ++s) {
        int r0 = s0[s][il], r1 = s1[s][il];
        bf16x8 u = *(const bf16x8*)(U + (size_t)r0 * JDIM + c0);
        bf16x8 v = *(const bf16x8*)(V + (size_t)r1 * JDIM + c0);
        #pragma unroll
        for (int p = 0; p < 8; ++p)
            acc[p] += fmaxf((float)u[p] + (float)v[p] + bias[p], 0.f);
    }

    bf16x8 o;
    #pragma unroll
    for (int p = 0; p < 8; ++p)
        o[p] = (__bf16)fmaxf(acc[p] * 0.125f, 0.f);
    *(bf16x8*)(E1b + (size_t)(i0 + il) * JDIM + c0) = o;
}

// ---------------------------------------------------------------------------
// Kernel 3 (MFMA, K=128), 64-row blocks:
//   E2 = relu(U + E1b @ Wg[128:,:] + bg);  out = E2 @ Wf + bf
// concat identity: concat(H,E1)@Wg = U + E1@Wg_bot.
// ---------------------------------------------------------------------------
__global__ __launch_bounds__(256) void k_final2(
    const __bf16* __restrict__ U, const __bf16* __restrict__ E1b,
    const __bf16* __restrict__ WtGb, const float* __restrict__ bg,
    const float* __restrict__ Wf, const float* __restrict__ bf,
    float* __restrict__ out)
{
    __shared__ __bf16 E2s[64][136];

    const int tid  = threadIdx.x;
    const int row0 = blockIdx.x * 64;
    const int wave = tid >> 6, lane = tid & 63;
    const int lm = lane & 15, lq = lane >> 4;

    // stage U tile 64x128 coalesced
    #pragma unroll
    for (int it = 0; it < 4; ++it) {
        int fid = it * 256 + tid;
        int row = fid >> 4, fr = fid & 15;
        int g = row0 + row; if (g >= L_NODES) g = L_NODES - 1;
        *(bf16x8*)&E2s[row][fr * 8] = *(const bf16x8*)(U + (size_t)g * JDIM + fr * 8);
    }

    // A-frags: one E1b row-tile per wave, K=128
    bf16x8 aall[4];
    {
        int grow = row0 + wave * 16 + lm;
        if (grow >= L_NODES) grow = L_NODES - 1;
        const __bf16* ep = E1b + (size_t)grow * JDIM + lq * 8;
        #pragma unroll
        for (int kc = 0; kc < 4; ++kc)
            aall[kc] = *(const bf16x8*)(ep + kc * 32);
    }

    const __bf16* bbase = WtGb + (size_t)lm * 128 + lq * 8;
    floatx4 acc[8] = {};
    bf16x8 bc[8], bn[8];
    #pragma unroll
    for (int nt = 0; nt < 8; ++nt)
        bc[nt] = *(const bf16x8*)(bbase + (size_t)nt * 16 * 128);
    #pragma unroll
    for (int ks = 0; ks < 4; ++ks) {
        if (ks < 3)
            #pragma unroll
            for (int nt = 0; nt < 8; ++nt)
                bn[nt] = *(const bf16x8*)(bbase + (size_t)nt * 16 * 128 + (ks + 1) * 32);
        #pragma unroll
        for (int nt = 0; nt < 8; ++nt)
            acc[nt] = __builtin_amdgcn_mfma_f32_16x16x32_bf16(aall[ks], bc[nt], acc[nt], 0, 0, 0);
        #pragma unroll
        for (int nt = 0; nt < 8; ++nt) bc[nt] = bn[nt];
    }
    __syncthreads();   // U staging visible

    // epilogue: E2s[r][c] = relu(U + acc + bias), in place (unique owner)
    #pragma unroll
    for (int nt = 0; nt < 8; ++nt) {
        int col = nt * 16 + lm;
        float bias = bg[col];
        #pragma unroll
        for (int p = 0; p < 4; ++p) {
            int r = wave * 16 + lq * 4 + p;
            float u = (float)E2s[r][col];
            E2s[r][col] = (__bf16)fmaxf(u + acc[nt][p] + bias, 0.f);
        }
    }
    __syncthreads();

    // head: out[row][o] = E2[row] . Wf[:,o] + bf[o]
    if (tid < 128) {
        int row = tid >> 1, o = tid & 1;
        int grow = row0 + row;
        if (grow < L_NODES) {
            float a = bf[o];
            #pragma unroll
            for (int j = 0; j < 16; ++j) {
                bf16x8 v = *(bf16x8*)&E2s[row][j * 8];
                #pragma unroll
                for (int c = 0; c < 8; ++c)
                    a = fmaf((float)v[c], Wf[(j * 8 + c) * 2 + o], a);
            }
            out[(size_t)grow * 2 + o] = a;
        }
    }
}

// ---------------------------------------------------------------------------
extern "C" void kernel_launch(void* const* d_in, const int* in_sizes, int n_in,
                              void* d_out, int out_size, void* d_ws, size_t ws_size,
                              hipStream_t stream) {
    const float* X    = (const float*)d_in[0];
    const float* W_h1 = (const float*)d_in[1];
    const float* b_h1 = (const float*)d_in[2];
    const float* W_g1 = (const float*)d_in[3];
    const float* b_g1 = (const float*)d_in[4];
    const float* W_f  = (const float*)d_in[5];
    const float* b_f  = (const float*)d_in[6];
    const int*   idx0 = (const int*)d_in[7];
    const int*   idx1 = (const int*)d_in[8];
    float* out = (float*)d_out;

    // d_ws layout (77.0 MB total; >=102.4 MB available per R1):
    __bf16* E1b = (__bf16*)d_ws;                          // 25.6 MB
    __bf16* U   = E1b + (size_t)L_NODES * JDIM;           // 25.6 MB (live to end)
    __bf16* V   = U   + (size_t)L_NODES * JDIM;           // 25.6 MB
    __bf16* WtH  = V + (size_t)L_NODES * JDIM;            // 64 KB
    __bf16* WtGu = WtH + 32768;                           // 64 KB
    __bf16* WtGb = WtGu + 32768;                          // 32 KB

    k_prep<<<128, 256, 0, stream>>>(W_h1, W_g1, WtH, WtGu, WtGb);
    k_h1uv<<<(L_NODES + 63) / 64, 256, 0, stream>>>(X, WtH, WtGu, b_h1, U, V);
    k_gather<<<L_NODES / 16, 256, 0, stream>>>(U, V, b_g1, idx0, idx1, E1b);
    k_final2<<<(L_NODES + 63) / 64, 256, 0, stream>>>(U, E1b, WtGb, b_g1, W_f, b_f, out);
}

// Round 10
// 343.055 us; speedup vs baseline: 1.0048x; 1.0048x over previous
//
#include <hip/hip_runtime.h>

#define L_NODES 100000
#define NFEAT   256
#define JDIM    128

typedef __bf16 bf16x8 __attribute__((ext_vector_type(8)));
typedef __bf16 bf16x4 __attribute__((ext_vector_type(4)));
typedef float  floatx4 __attribute__((ext_vector_type(4)));

// Column permutation for barrier-free C-layout stores:
//   true col c = hi*16+lo  ->  stored col' = pi(c) = lo*8 + hi
//   pi^{-1}(c') : lo = c'>>3, hi = c'&7 -> c = (c'&7)*16 + (c'>>3)
// All intermediates (U,V,E1) live in pi-permuted layout; weights' k-dims and
// the gather bias are permuted in prep so every kernel stays consistent.

// ---------------------------------------------------------------------------
// Prep:
//   WtH  [128][256]: WtH[n][k]   = bf16(W_h1[k][n])          (k unpermuted)
//   WtGu2[128][128]: WtGu2[n][pi(k)] = bf16(W_g1[k][n])      k in [0,128)
//   WtGv [128][128]: WtGv [n][pi(k)] = bf16(W_g1[128+k][n])
//   bgp  [128] fp32: bgp[pi(k)] = b_g1[k]
// ---------------------------------------------------------------------------
__global__ __launch_bounds__(256) void k_prep(
    const float* __restrict__ Wh, const float* __restrict__ Wg,
    const float* __restrict__ bg,
    __bf16* __restrict__ WtH, __bf16* __restrict__ WtGu2,
    __bf16* __restrict__ WtGv, float* __restrict__ bgp)
{
    int i = blockIdx.x * 256 + threadIdx.x;   // 32768
    int n = i >> 8, k = i & 255;
    WtH[i] = (__bf16)Wh[k * JDIM + n];
    if (i < 16384) {
        int n2 = i >> 7, k2 = i & 127;
        int kp = (k2 & 15) * 8 + (k2 >> 4);
        WtGu2[n2 * 128 + kp] = (__bf16)Wg[k2 * JDIM + n2];
        WtGv [n2 * 128 + kp] = (__bf16)Wg[(128 + k2) * JDIM + n2];
    }
    if (i < 128) {
        int kp = (i & 15) * 8 + (i >> 4);
        bgp[kp] = bg[i];
    }
}

// ---------------------------------------------------------------------------
// Kernel 1 (fused, BARRIER-FREE): per 64-row block, wave = 16 rows:
//   phase 1: H = relu(X @ W_h1 + b)  (K=256), A direct global->VGPR
//   H -> wave-private LDS patch in pi-layout (wave-local, no barrier)
//   phase 2: U' = H @ WgU, V' = H @ WgV (K=128), stores straight from
//            accumulators as contiguous 16B (pi-layout), coalesced.
// ---------------------------------------------------------------------------
__global__ __launch_bounds__(256) void k_h1uv(
    const float* __restrict__ X, const __bf16* __restrict__ WtH,
    const __bf16* __restrict__ WtGu2, const __bf16* __restrict__ WtGv,
    const float* __restrict__ b, __bf16* __restrict__ U, __bf16* __restrict__ V)
{
    __shared__ __bf16 patch[4][16 * 136];   // per-wave 16x128 H tile (pi-layout)

    const int tid  = threadIdx.x;
    const int row0 = blockIdx.x * 64;
    const int wave = tid >> 6, lane = tid & 63;
    const int lm = lane & 15, lq = lane >> 4;

    // A: X row (row0 + wave*16 + lm), all K=256, fp32 -> bf16 frags
    int arow = row0 + wave * 16 + lm;
    if (arow >= L_NODES) arow = L_NODES - 1;
    const float* xp = X + (size_t)arow * NFEAT + lq * 8;
    bf16x8 aall[8];
    #pragma unroll
    for (int ks = 0; ks < 8; ++ks) {
        float4 v0 = *(const float4*)(xp + ks * 32);
        float4 v1 = *(const float4*)(xp + ks * 32 + 4);
        bf16x8 a;
        a[0]=(__bf16)v0.x; a[1]=(__bf16)v0.y; a[2]=(__bf16)v0.z; a[3]=(__bf16)v0.w;
        a[4]=(__bf16)v1.x; a[5]=(__bf16)v1.y; a[6]=(__bf16)v1.z; a[7]=(__bf16)v1.w;
        aall[ks] = a;
    }

    // phase 1
    floatx4 acc[8] = {};
    #pragma unroll
    for (int ks = 0; ks < 8; ++ks) {
        bf16x8 bc[8];
        #pragma unroll
        for (int nt = 0; nt < 8; ++nt)
            bc[nt] = *(const bf16x8*)(WtH + (size_t)(nt * 16 + lm) * 256 + ks * 32 + lq * 8);
        #pragma unroll
        for (int nt = 0; nt < 8; ++nt)
            acc[nt] = __builtin_amdgcn_mfma_f32_16x16x32_bf16(aall[ks], bc[nt], acc[nt], 0, 0, 0);
    }

    // bias + relu -> wave-private patch, pi-layout (row_local = lq*4+p,
    // col' = lm*8 + nt  ==> one 16B ds_write per p). Wave-local only.
    {
        float bias[8];
        #pragma unroll
        for (int nt = 0; nt < 8; ++nt) bias[nt] = b[nt * 16 + lm];
        #pragma unroll
        for (int p = 0; p < 4; ++p) {
            bf16x8 hv;
            #pragma unroll
            for (int nt = 0; nt < 8; ++nt)
                hv[nt] = (__bf16)fmaxf(acc[nt][p] + bias[nt], 0.f);
            *(bf16x8*)&patch[wave][(lq * 4 + p) * 136 + lm * 8] = hv;
        }
    }

    // A-frags for phase 2: H'[m=lm][k' = kc*32 + lq*8 ...]
    bf16x8 haf[4];
    #pragma unroll
    for (int kc = 0; kc < 4; ++kc)
        haf[kc] = *(const bf16x8*)&patch[wave][lm * 136 + kc * 32 + lq * 8];

    // phase 2a: U' = H' @ WtGu2
    floatx4 acc2[8] = {};
    #pragma unroll
    for (int ks = 0; ks < 4; ++ks) {
        bf16x8 bc[8];
        #pragma unroll
        for (int nt = 0; nt < 8; ++nt)
            bc[nt] = *(const bf16x8*)(WtGu2 + (size_t)(nt * 16 + lm) * 128 + ks * 32 + lq * 8);
        #pragma unroll
        for (int nt = 0; nt < 8; ++nt)
            acc2[nt] = __builtin_amdgcn_mfma_f32_16x16x32_bf16(haf[ks], bc[nt], acc2[nt], 0, 0, 0);
    }
    #pragma unroll
    for (int p = 0; p < 4; ++p) {
        int grow = row0 + wave * 16 + lq * 4 + p;
        if (grow < L_NODES) {
            bf16x8 o;
            #pragma unroll
            for (int nt = 0; nt < 8; ++nt) o[nt] = (__bf16)acc2[nt][p];
            *(bf16x8*)(U + (size_t)grow * JDIM + lm * 8) = o;   // col' = lm*8+nt
        }
    }

    // phase 2b: V' = H' @ WtGv
    floatx4 acc3[8] = {};
    #pragma unroll
    for (int ks = 0; ks < 4; ++ks) {
        bf16x8 bc[8];
        #pragma unroll
        for (int nt = 0; nt < 8; ++nt)
            bc[nt] = *(const bf16x8*)(WtGv + (size_t)(nt * 16 + lm) * 128 + ks * 32 + lq * 8);
        #pragma unroll
        for (int nt = 0; nt < 8; ++nt)
            acc3[nt] = __builtin_amdgcn_mfma_f32_16x16x32_bf16(haf[ks], bc[nt], acc3[nt], 0, 0, 0);
    }
    #pragma unroll
    for (int p = 0; p < 4; ++p) {
        int grow = row0 + wave * 16 + lq * 4 + p;
        if (grow < L_NODES) {
            bf16x8 o;
            #pragma unroll
            for (int nt = 0; nt < 8; ++nt) o[nt] = (__bf16)acc3[nt][p];
            *(bf16x8*)(V + (size_t)grow * JDIM + lm * 8) = o;
        }
    }
}

// ---------------------------------------------------------------------------
// Kernel 2 (gather-add, layout-agnostic): E1'[i] = relu(mean_s relu(U'+V'+bgp))
// R5-proven config. Random-BW bound — measured floor ~61 us.
// ---------------------------------------------------------------------------
__global__ __launch_bounds__(256) void k_gather(
    const __bf16* __restrict__ U, const __bf16* __restrict__ V,
    const float* __restrict__ bgp,
    const int* __restrict__ idx0, const int* __restrict__ idx1,
    __bf16* __restrict__ E1b)
{
    __shared__ int s0[8][16], s1[8][16];

    const int tid = threadIdx.x;
    const int i0  = blockIdx.x * 16;

    if (tid < 128) {
        int s = tid >> 4, il = tid & 15;
        s0[s][il] = idx0[(size_t)s * L_NODES + i0 + il];
    } else {
        int t = tid - 128, s = t >> 4, il = t & 15;
        s1[s][il] = idx1[(size_t)s * L_NODES + i0 + il];
    }
    __syncthreads();

    const int il = tid >> 4;
    const int c0 = (tid & 15) * 8;

    float bias[8];
    *(float4*)&bias[0] = *(const float4*)(bgp + c0);
    *(float4*)&bias[4] = *(const float4*)(bgp + c0 + 4);

    float acc[8] = {};
    #pragma unroll
    for (int s = 0; s < 8; ++s) {
        int r0 = s0[s][il], r1 = s1[s][il];
        bf16x8 u = *(const bf16x8*)(U + (size_t)r0 * JDIM + c0);
        bf16x8 v = *(const bf16x8*)(V + (size_t)r1 * JDIM + c0);
        #pragma unroll
        for (int p = 0; p < 8; ++p)
            acc[p] += fmaxf((float)u[p] + (float)v[p] + bias[p], 0.f);
    }

    bf16x8 o;
    #pragma unroll
    for (int p = 0; p < 8; ++p)
        o[p] = (__bf16)fmaxf(acc[p] * 0.125f, 0.f);
    *(bf16x8*)(E1b + (size_t)(i0 + il) * JDIM + c0) = o;
}

// ---------------------------------------------------------------------------
// Kernel 3 (BARRIER-FREE, no LDS): E2 = relu(U + E1 @ Wg_bot + bg);
// out = E2 @ Wf + bf.  A = E1' (k' matches WtGv's permuted k), U' read back
// in the writer's own pattern, head reduced via shfl_xor within 16-lane groups.
// ---------------------------------------------------------------------------
__global__ __launch_bounds__(256) void k_final2(
    const __bf16* __restrict__ U, const __bf16* __restrict__ E1b,
    const __bf16* __restrict__ WtGv, const float* __restrict__ bg,
    const float* __restrict__ Wf, const float* __restrict__ bf,
    float* __restrict__ out)
{
    const int tid  = threadIdx.x;
    const int row0 = blockIdx.x * 64;
    const int wave = tid >> 6, lane = tid & 63;
    const int lm = lane & 15, lq = lane >> 4;

    int arow = row0 + wave * 16 + lm;
    if (arow >= L_NODES) arow = L_NODES - 1;
    const __bf16* ep = E1b + (size_t)arow * JDIM + lq * 8;
    bf16x8 aall[4];
    #pragma unroll
    for (int kc = 0; kc < 4; ++kc)
        aall[kc] = *(const bf16x8*)(ep + kc * 32);

    floatx4 acc[8] = {};
    #pragma unroll
    for (int ks = 0; ks < 4; ++ks) {
        bf16x8 bc[8];
        #pragma unroll
        for (int nt = 0; nt < 8; ++nt)
            bc[nt] = *(const bf16x8*)(WtGv + (size_t)(nt * 16 + lm) * 128 + ks * 32 + lq * 8);
        #pragma unroll
        for (int nt = 0; nt < 8; ++nt)
            acc[nt] = __builtin_amdgcn_mfma_f32_16x16x32_bf16(aall[ks], bc[nt], acc[nt], 0, 0, 0);
    }

    // epilogue + head, all in registers
    float bias[8], wf0[8], wf1[8];
    #pragma unroll
    for (int nt = 0; nt < 8; ++nt) {
        int col = nt * 16 + lm;
        bias[nt] = bg[col];
        wf0[nt] = Wf[col * 2 + 0];
        wf1[nt] = Wf[col * 2 + 1];
    }

    float part0[4], part1[4];
    #pragma unroll
    for (int p = 0; p < 4; ++p) {
        int grow = row0 + wave * 16 + lq * 4 + p;
        int gl = grow < L_NODES ? grow : L_NODES - 1;
        bf16x8 u = *(const bf16x8*)(U + (size_t)gl * JDIM + lm * 8);  // u[nt]=U[row][nt*16+lm]
        float a0 = 0.f, a1 = 0.f;
        #pragma unroll
        for (int nt = 0; nt < 8; ++nt) {
            float e2 = fmaxf((float)u[nt] + acc[nt][p] + bias[nt], 0.f);
            a0 = fmaf(e2, wf0[nt], a0);
            a1 = fmaf(e2, wf1[nt], a1);
        }
        part0[p] = a0; part1[p] = a1;
    }
    // reduce across the 16 lm lanes (butterfly within 16-lane groups)
    #pragma unroll
    for (int m = 1; m <= 8; m <<= 1) {
        #pragma unroll
        for (int p = 0; p < 4; ++p) {
            part0[p] += __shfl_xor(part0[p], m, 16);
            part1[p] += __shfl_xor(part1[p], m, 16);
        }
    }
    if (lm == 0) {
        float bf0 = bf[0], bf1 = bf[1];
        #pragma unroll
        for (int p = 0; p < 4; ++p) {
            int grow = row0 + wave * 16 + lq * 4 + p;
            if (grow < L_NODES) {
                out[(size_t)grow * 2 + 0] = part0[p] + bf0;
                out[(size_t)grow * 2 + 1] = part1[p] + bf1;
            }
        }
    }
}

// ---------------------------------------------------------------------------
extern "C" void kernel_launch(void* const* d_in, const int* in_sizes, int n_in,
                              void* d_out, int out_size, void* d_ws, size_t ws_size,
                              hipStream_t stream) {
    const float* X    = (const float*)d_in[0];
    const float* W_h1 = (const float*)d_in[1];
    const float* b_h1 = (const float*)d_in[2];
    const float* W_g1 = (const float*)d_in[3];
    const float* b_g1 = (const float*)d_in[4];
    const float* W_f  = (const float*)d_in[5];
    const float* b_f  = (const float*)d_in[6];
    const int*   idx0 = (const int*)d_in[7];
    const int*   idx1 = (const int*)d_in[8];
    float* out = (float*)d_out;

    __bf16* E1b   = (__bf16*)d_ws;                        // 25.6 MB (pi-layout)
    __bf16* U     = E1b + (size_t)L_NODES * JDIM;         // 25.6 MB (pi-layout)
    __bf16* V     = U   + (size_t)L_NODES * JDIM;         // 25.6 MB (pi-layout)
    __bf16* WtH   = V   + (size_t)L_NODES * JDIM;         // 64 KB
    __bf16* WtGu2 = WtH + 32768;                          // 32 KB
    __bf16* WtGv  = WtGu2 + 16384;                        // 32 KB
    float*  bgp   = (float*)(WtGv + 16384);               // 512 B

    k_prep<<<128, 256, 0, stream>>>(W_h1, W_g1, b_g1, WtH, WtGu2, WtGv, bgp);
    k_h1uv<<<(L_NODES + 63) / 64, 256, 0, stream>>>(X, WtH, WtGu2, WtGv, b_h1, U, V);
    k_gather<<<L_NODES / 16, 256, 0, stream>>>(U, V, bgp, idx0, idx1, E1b);
    k_final2<<<(L_NODES + 63) / 64, 256, 0, stream>>>(U, E1b, WtGv, b_g1, W_f, b_f, out);
}

// Round 11
// 276.351 us; speedup vs baseline: 1.2473x; 1.2414x over previous
//
#include <hip/hip_runtime.h>

#define L_NODES 100000
#define NFEAT   256
#define JDIM    128

typedef __bf16 bf16x8 __attribute__((ext_vector_type(8)));
typedef __bf16 bf16x4 __attribute__((ext_vector_type(4)));
typedef float  floatx4 __attribute__((ext_vector_type(4)));

// ---------------------------------------------------------------------------
// Prep:
//   WtH [128][256]: WtH[n][k]  = bf16(W_h1[k][n])
//   WtG2[256][128]: n<128: Wg[k][n]   (U cols);  n>=128: Wg[128+k][n-128] (V cols)
//     (note rows 128.. of WtG2 double as WtGv[n][k]=Wg[128+k][n] for final2)
// ---------------------------------------------------------------------------
__global__ __launch_bounds__(256) void k_prep(
    const float* __restrict__ Wh, const float* __restrict__ Wg,
    __bf16* __restrict__ WtH, __bf16* __restrict__ WtG2)
{
    int i = blockIdx.x * 256 + threadIdx.x;   // 32768
    int n = i >> 8, k = i & 255;
    WtH[i] = (__bf16)Wh[k * JDIM + n];
    int n2 = i >> 7, k2 = i & 127;
    WtG2[i] = (n2 < 128) ? (__bf16)Wg[k2 * JDIM + n2]
                         : (__bf16)Wg[(128 + k2) * JDIM + (n2 - 128)];
}

// ---------------------------------------------------------------------------
// Kernel 1 (fused h1+uv). 64-row blocks. Global accesses are BULK only
// (cooperative staging, 16 loads/thread in flight); B panels live in VGPRs
// (loaded once per block); MFMA loop reads A from LDS.
//   phase 1: H = relu(X @ W_h1 + b)  (K=256, N=128); wave = 4 m-tiles x 2 nt
//   phase 2: U||V = H @ WtG2         (K=128, N=256); wave = 4 m-tiles x 4 nt
// ---------------------------------------------------------------------------
__global__ __launch_bounds__(256) void k_h1uv(
    const float* __restrict__ X, const __bf16* __restrict__ WtH,
    const __bf16* __restrict__ WtG2, const float* __restrict__ b,
    __bf16* __restrict__ U, __bf16* __restrict__ V)
{
    __shared__ __bf16 As[64 * 264];   // X tile [64][256] s264; reused for output
    __shared__ __bf16 Hs[64 * 136];   // H tile [64][128] s136

    const int tid  = threadIdx.x;
    const int row0 = blockIdx.x * 64;
    const int wave = tid >> 6, lane = tid & 63;
    const int lm = lane & 15, lq = lane >> 4;

    // B1 panel resident: wave covers nt in {2w, 2w+1}; 16 frags = 64 VGPR
    bf16x8 b1[2][8];
    #pragma unroll
    for (int nt = 0; nt < 2; ++nt) {
        int ntg = wave * 2 + nt;
        #pragma unroll
        for (int ks = 0; ks < 8; ++ks)
            b1[nt][ks] = *(const bf16x8*)(WtH + (size_t)(ntg * 16 + lm) * 256 + ks * 32 + lq * 8);
    }

    // bulk stage X: 64 rows x 256 cols fp32 -> bf16 (16 float4 loads/thread)
    #pragma unroll
    for (int it = 0; it < 16; ++it) {
        int f4  = it * 256 + tid;
        int row = f4 >> 6, c4 = f4 & 63;
        int grow = row0 + row; if (grow >= L_NODES) grow = L_NODES - 1;
        float4 v = *(const float4*)(X + (size_t)grow * NFEAT + c4 * 4);
        bf16x4 o; o[0]=(__bf16)v.x; o[1]=(__bf16)v.y; o[2]=(__bf16)v.z; o[3]=(__bf16)v.w;
        *(bf16x4*)&As[row * 264 + c4 * 4] = o;
    }
    __syncthreads();

    // phase 1: acc1[mt][nt]
    floatx4 acc1[4][2] = {};
    #pragma unroll
    for (int ks = 0; ks < 8; ++ks) {
        bf16x8 af[4];
        #pragma unroll
        for (int t = 0; t < 4; ++t)
            af[t] = *(const bf16x8*)&As[(t * 16 + lm) * 264 + ks * 32 + lq * 8];
        #pragma unroll
        for (int t = 0; t < 4; ++t)
            #pragma unroll
            for (int nt = 0; nt < 2; ++nt)
                acc1[t][nt] = __builtin_amdgcn_mfma_f32_16x16x32_bf16(
                    af[t], b1[nt][ks], acc1[t][nt], 0, 0, 0);
    }

    // B2 panel resident: wave covers nt2 in {4w..4w+3}; 16 frags = 64 VGPR
    bf16x8 b2[4][4];
    #pragma unroll
    for (int nt = 0; nt < 4; ++nt) {
        int ntg = wave * 4 + nt;
        #pragma unroll
        for (int ks = 0; ks < 4; ++ks)
            b2[nt][ks] = *(const bf16x8*)(WtG2 + (size_t)(ntg * 16 + lm) * 128 + ks * 32 + lq * 8);
    }

    // H (bias+relu) -> Hs
    #pragma unroll
    for (int nt = 0; nt < 2; ++nt) {
        int col = (wave * 2 + nt) * 16 + lm;
        float bias = b[col];
        #pragma unroll
        for (int t = 0; t < 4; ++t)
            #pragma unroll
            for (int p = 0; p < 4; ++p)
                Hs[(t * 16 + lq * 4 + p) * 136 + col] =
                    (__bf16)fmaxf(acc1[t][nt][p] + bias, 0.f);
    }
    __syncthreads();

    // phase 2: acc2[mt][nt2], K=128 from Hs
    floatx4 acc2[4][4] = {};
    #pragma unroll
    for (int ks = 0; ks < 4; ++ks) {
        bf16x8 af[4];
        #pragma unroll
        for (int t = 0; t < 4; ++t)
            af[t] = *(const bf16x8*)&Hs[(t * 16 + lm) * 136 + ks * 32 + lq * 8];
        #pragma unroll
        for (int t = 0; t < 4; ++t)
            #pragma unroll
            for (int nt = 0; nt < 4; ++nt)
                acc2[t][nt] = __builtin_amdgcn_mfma_f32_16x16x32_bf16(
                    af[t], b2[nt][ks], acc2[t][nt], 0, 0, 0);
    }

    // acc2 -> As as [64][256] s264 (As reads finished at phase-1 end)
    #pragma unroll
    for (int nt = 0; nt < 4; ++nt) {
        int col = (wave * 4 + nt) * 16 + lm;
        #pragma unroll
        for (int t = 0; t < 4; ++t)
            #pragma unroll
            for (int p = 0; p < 4; ++p)
                As[(t * 16 + lq * 4 + p) * 264 + col] = (__bf16)acc2[t][nt][p];
    }
    __syncthreads();

    // bulk store U (cols 0..127) / V (cols 128..255): 8 bf16x8 stores/thread
    #pragma unroll
    for (int it = 0; it < 8; ++it) {
        int fid = it * 256 + tid;
        int row = fid >> 5, c8 = fid & 31;
        int grow = row0 + row;
        if (grow < L_NODES) {
            int col = c8 * 8;
            bf16x8 v = *(bf16x8*)&As[row * 264 + col];
            if (col < 128) *(bf16x8*)(U + (size_t)grow * JDIM + col) = v;
            else           *(bf16x8*)(V + (size_t)grow * JDIM + (col - 128)) = v;
        }
    }
}

// ---------------------------------------------------------------------------
// Kernel 2 (gather-add): E1[i] = bf16(relu(mean_s relu(U[idx0]+V[idx1]+b)))
// R5-proven config. Random-BW bound — measured floor ~61 us.
// ---------------------------------------------------------------------------
__global__ __launch_bounds__(256) void k_gather(
    const __bf16* __restrict__ U, const __bf16* __restrict__ V,
    const float* __restrict__ b,
    const int* __restrict__ idx0, const int* __restrict__ idx1,
    __bf16* __restrict__ E1b)
{
    __shared__ int s0[8][16], s1[8][16];

    const int tid = threadIdx.x;
    const int i0  = blockIdx.x * 16;

    if (tid < 128) {
        int s = tid >> 4, il = tid & 15;
        s0[s][il] = idx0[(size_t)s * L_NODES + i0 + il];
    } else {
        int t = tid - 128, s = t >> 4, il = t & 15;
        s1[s][il] = idx1[(size_t)s * L_NODES + i0 + il];
    }
    __syncthreads();

    const int il = tid >> 4;
    const int c0 = (tid & 15) * 8;

    float bias[8];
    *(float4*)&bias[0] = *(const float4*)(b + c0);
    *(float4*)&bias[4] = *(const float4*)(b + c0 + 4);

    float acc[8] = {};
    #pragma unroll
    for (int s = 0; s < 8; ++s) {
        int r0 = s0[s][il], r1 = s1[s][il];
        bf16x8 u = *(const bf16x8*)(U + (size_t)r0 * JDIM + c0);
        bf16x8 v = *(const bf16x8*)(V + (size_t)r1 * JDIM + c0);
        #pragma unroll
        for (int p = 0; p < 8; ++p)
            acc[p] += fmaxf((float)u[p] + (float)v[p] + bias[p], 0.f);
    }

    bf16x8 o;
    #pragma unroll
    for (int p = 0; p < 8; ++p)
        o[p] = (__bf16)fmaxf(acc[p] * 0.125f, 0.f);
    *(bf16x8*)(E1b + (size_t)(i0 + il) * JDIM + c0) = o;
}

// ---------------------------------------------------------------------------
// Kernel 3: E2 = relu(U + E1 @ Wg_bot + bg); out = E2 @ Wf + bf.
// Same bulk/LDS/B-resident pattern. Wave = 4 m-tiles x 2 nt; head reduced
// via shfl within 16-lane groups + 2 KB LDS partials across waves.
// WtGv == WtG2 + 128*128 (rows 128.. are exactly Wg[128+k][n]).
// ---------------------------------------------------------------------------
__global__ __launch_bounds__(256) void k_final2(
    const __bf16* __restrict__ U, const __bf16* __restrict__ E1b,
    const __bf16* __restrict__ WtGv, const float* __restrict__ bg,
    const float* __restrict__ Wf, const float* __restrict__ bf,
    float* __restrict__ out)
{
    __shared__ __bf16 E1s[64 * 136];
    __shared__ __bf16 Us [64 * 136];
    __shared__ float  part[4][64][2];

    const int tid  = threadIdx.x;
    const int row0 = blockIdx.x * 64;
    const int wave = tid >> 6, lane = tid & 63;
    const int lm = lane & 15, lq = lane >> 4;

    // B panel resident: 8 frags = 32 VGPR
    bf16x8 b3[2][4];
    #pragma unroll
    for (int nt = 0; nt < 2; ++nt) {
        int ntg = wave * 2 + nt;
        #pragma unroll
        for (int ks = 0; ks < 4; ++ks)
            b3[nt][ks] = *(const bf16x8*)(WtGv + (size_t)(ntg * 16 + lm) * 128 + ks * 32 + lq * 8);
    }

    // bulk stage E1 and U tiles (8 bf16x8 loads/thread)
    #pragma unroll
    for (int it = 0; it < 8; ++it) {
        int fid = it * 256 + tid;            // 0..2047
        int half = fid >> 10;                // 0: E1, 1: U
        int r = (fid & 1023) >> 4, c8 = fid & 15;
        int grow = row0 + r; if (grow >= L_NODES) grow = L_NODES - 1;
        const __bf16* src = half ? (U + (size_t)grow * JDIM + c8 * 8)
                                 : (E1b + (size_t)grow * JDIM + c8 * 8);
        __bf16* dst = half ? &Us[r * 136 + c8 * 8] : &E1s[r * 136 + c8 * 8];
        *(bf16x8*)dst = *(const bf16x8*)src;
    }
    __syncthreads();

    floatx4 acc[4][2] = {};
    #pragma unroll
    for (int ks = 0; ks < 4; ++ks) {
        bf16x8 af[4];
        #pragma unroll
        for (int t = 0; t < 4; ++t)
            af[t] = *(const bf16x8*)&E1s[(t * 16 + lm) * 136 + ks * 32 + lq * 8];
        #pragma unroll
        for (int t = 0; t < 4; ++t)
            #pragma unroll
            for (int nt = 0; nt < 2; ++nt)
                acc[t][nt] = __builtin_amdgcn_mfma_f32_16x16x32_bf16(
                    af[t], b3[nt][ks], acc[t][nt], 0, 0, 0);
    }

    // epilogue + head partials over this wave's 32 cols
    float bias[2], wf0[2], wf1[2];
    #pragma unroll
    for (int nt = 0; nt < 2; ++nt) {
        int col = (wave * 2 + nt) * 16 + lm;
        bias[nt] = bg[col];
        wf0[nt] = Wf[col * 2 + 0];
        wf1[nt] = Wf[col * 2 + 1];
    }
    #pragma unroll
    for (int t = 0; t < 4; ++t) {
        float p0[4], p1[4];
        #pragma unroll
        for (int p = 0; p < 4; ++p) {
            int r = t * 16 + lq * 4 + p;
            float a0 = 0.f, a1 = 0.f;
            #pragma unroll
            for (int nt = 0; nt < 2; ++nt) {
                int col = (wave * 2 + nt) * 16 + lm;
                float e2 = fmaxf((float)Us[r * 136 + col] + acc[t][nt][p] + bias[nt], 0.f);
                a0 = fmaf(e2, wf0[nt], a0);
                a1 = fmaf(e2, wf1[nt], a1);
            }
            p0[p] = a0; p1[p] = a1;
        }
        #pragma unroll
        for (int m = 1; m <= 8; m <<= 1)
            #pragma unroll
            for (int p = 0; p < 4; ++p) {
                p0[p] += __shfl_xor(p0[p], m, 16);
                p1[p] += __shfl_xor(p1[p], m, 16);
            }
        if (lm == 0)
            #pragma unroll
            for (int p = 0; p < 4; ++p) {
                part[wave][t * 16 + lq * 4 + p][0] = p0[p];
                part[wave][t * 16 + lq * 4 + p][1] = p1[p];
            }
    }
    __syncthreads();

    if (tid < 128) {
        int row = tid >> 1, o = tid & 1;
        int grow = row0 + row;
        if (grow < L_NODES)
            out[(size_t)grow * 2 + o] =
                part[0][row][o] + part[1][row][o] + part[2][row][o] + part[3][row][o] + bf[o];
    }
}

// ---------------------------------------------------------------------------
extern "C" void kernel_launch(void* const* d_in, const int* in_sizes, int n_in,
                              void* d_out, int out_size, void* d_ws, size_t ws_size,
                              hipStream_t stream) {
    const float* X    = (const float*)d_in[0];
    const float* W_h1 = (const float*)d_in[1];
    const float* b_h1 = (const float*)d_in[2];
    const float* W_g1 = (const float*)d_in[3];
    const float* b_g1 = (const float*)d_in[4];
    const float* W_f  = (const float*)d_in[5];
    const float* b_f  = (const float*)d_in[6];
    const int*   idx0 = (const int*)d_in[7];
    const int*   idx1 = (const int*)d_in[8];
    float* out = (float*)d_out;

    __bf16* E1b  = (__bf16*)d_ws;                         // 25.6 MB
    __bf16* U    = E1b + (size_t)L_NODES * JDIM;          // 25.6 MB
    __bf16* V    = U   + (size_t)L_NODES * JDIM;          // 25.6 MB
    __bf16* WtH  = V   + (size_t)L_NODES * JDIM;          // 64 KB
    __bf16* WtG2 = WtH + 32768;                           // 64 KB
    __bf16* WtGv = WtG2 + 128 * 128;                      // alias: rows 128.. of WtG2

    k_prep<<<128, 256, 0, stream>>>(W_h1, W_g1, WtH, WtG2);
    k_h1uv<<<(L_NODES + 63) / 64, 256, 0, stream>>>(X, WtH, WtG2, b_h1, U, V);
    k_gather<<<L_NODES / 16, 256, 0, stream>>>(U, V, b_g1, idx0, idx1, E1b);
    k_final2<<<(L_NODES + 63) / 64, 256, 0, stream>>>(U, E1b, WtGv, b_g1, W_f, b_f, out);
}

// Round 12
// 267.847 us; speedup vs baseline: 1.2869x; 1.0317x over previous
//
#include <hip/hip_runtime.h>

#define L_NODES 100000
#define NFEAT   256
#define JDIM    128

typedef __bf16 bf16x8 __attribute__((ext_vector_type(8)));
typedef __bf16 bf16x4 __attribute__((ext_vector_type(4)));
typedef float  floatx4 __attribute__((ext_vector_type(4)));

// ---------------------------------------------------------------------------
// Prep:
//   WtH [128][256]: WtH[n][k]  = bf16(W_h1[k][n])
//   WtG2[256][128]: n<128: Wg[k][n]   (U cols);  n>=128: Wg[128+k][n-128] (V cols)
//     rows 128.. of WtG2 double as WtGv[n][k]=Wg[128+k][n] for k_gfinal.
// ---------------------------------------------------------------------------
__global__ __launch_bounds__(256) void k_prep(
    const float* __restrict__ Wh, const float* __restrict__ Wg,
    __bf16* __restrict__ WtH, __bf16* __restrict__ WtG2)
{
    int i = blockIdx.x * 256 + threadIdx.x;   // 32768
    int n = i >> 8, k = i & 255;
    WtH[i] = (__bf16)Wh[k * JDIM + n];
    int n2 = i >> 7, k2 = i & 127;
    WtG2[i] = (n2 < 128) ? (__bf16)Wg[k2 * JDIM + n2]
                         : (__bf16)Wg[(128 + k2) * JDIM + (n2 - 128)];
}

// ---------------------------------------------------------------------------
// Kernel 1 (fused h1+uv) — R11-proven (82 us). Bulk staging only; B panels
// register-resident; MFMA reads A from LDS.
// ---------------------------------------------------------------------------
__global__ __launch_bounds__(256) void k_h1uv(
    const float* __restrict__ X, const __bf16* __restrict__ WtH,
    const __bf16* __restrict__ WtG2, const float* __restrict__ b,
    __bf16* __restrict__ U, __bf16* __restrict__ V)
{
    __shared__ __bf16 As[64 * 264];
    __shared__ __bf16 Hs[64 * 136];

    const int tid  = threadIdx.x;
    const int row0 = blockIdx.x * 64;
    const int wave = tid >> 6, lane = tid & 63;
    const int lm = lane & 15, lq = lane >> 4;

    bf16x8 b1[2][8];
    #pragma unroll
    for (int nt = 0; nt < 2; ++nt) {
        int ntg = wave * 2 + nt;
        #pragma unroll
        for (int ks = 0; ks < 8; ++ks)
            b1[nt][ks] = *(const bf16x8*)(WtH + (size_t)(ntg * 16 + lm) * 256 + ks * 32 + lq * 8);
    }

    #pragma unroll
    for (int it = 0; it < 16; ++it) {
        int f4  = it * 256 + tid;
        int row = f4 >> 6, c4 = f4 & 63;
        int grow = row0 + row; if (grow >= L_NODES) grow = L_NODES - 1;
        float4 v = *(const float4*)(X + (size_t)grow * NFEAT + c4 * 4);
        bf16x4 o; o[0]=(__bf16)v.x; o[1]=(__bf16)v.y; o[2]=(__bf16)v.z; o[3]=(__bf16)v.w;
        *(bf16x4*)&As[row * 264 + c4 * 4] = o;
    }
    __syncthreads();

    floatx4 acc1[4][2] = {};
    #pragma unroll
    for (int ks = 0; ks < 8; ++ks) {
        bf16x8 af[4];
        #pragma unroll
        for (int t = 0; t < 4; ++t)
            af[t] = *(const bf16x8*)&As[(t * 16 + lm) * 264 + ks * 32 + lq * 8];
        #pragma unroll
        for (int t = 0; t < 4; ++t)
            #pragma unroll
            for (int nt = 0; nt < 2; ++nt)
                acc1[t][nt] = __builtin_amdgcn_mfma_f32_16x16x32_bf16(
                    af[t], b1[nt][ks], acc1[t][nt], 0, 0, 0);
    }

    bf16x8 b2[4][4];
    #pragma unroll
    for (int nt = 0; nt < 4; ++nt) {
        int ntg = wave * 4 + nt;
        #pragma unroll
        for (int ks = 0; ks < 4; ++ks)
            b2[nt][ks] = *(const bf16x8*)(WtG2 + (size_t)(ntg * 16 + lm) * 128 + ks * 32 + lq * 8);
    }

    #pragma unroll
    for (int nt = 0; nt < 2; ++nt) {
        int col = (wave * 2 + nt) * 16 + lm;
        float bias = b[col];
        #pragma unroll
        for (int t = 0; t < 4; ++t)
            #pragma unroll
            for (int p = 0; p < 4; ++p)
                Hs[(t * 16 + lq * 4 + p) * 136 + col] =
                    (__bf16)fmaxf(acc1[t][nt][p] + bias, 0.f);
    }
    __syncthreads();

    floatx4 acc2[4][4] = {};
    #pragma unroll
    for (int ks = 0; ks < 4; ++ks) {
        bf16x8 af[4];
        #pragma unroll
        for (int t = 0; t < 4; ++t)
            af[t] = *(const bf16x8*)&Hs[(t * 16 + lm) * 136 + ks * 32 + lq * 8];
        #pragma unroll
        for (int t = 0; t < 4; ++t)
            #pragma unroll
            for (int nt = 0; nt < 4; ++nt)
                acc2[t][nt] = __builtin_amdgcn_mfma_f32_16x16x32_bf16(
                    af[t], b2[nt][ks], acc2[t][nt], 0, 0, 0);
    }

    #pragma unroll
    for (int nt = 0; nt < 4; ++nt) {
        int col = (wave * 4 + nt) * 16 + lm;
        #pragma unroll
        for (int t = 0; t < 4; ++t)
            #pragma unroll
            for (int p = 0; p < 4; ++p)
                As[(t * 16 + lq * 4 + p) * 264 + col] = (__bf16)acc2[t][nt][p];
    }
    __syncthreads();

    #pragma unroll
    for (int it = 0; it < 8; ++it) {
        int fid = it * 256 + tid;
        int row = fid >> 5, c8 = fid & 31;
        int grow = row0 + row;
        if (grow < L_NODES) {
            int col = c8 * 8;
            bf16x8 v = *(bf16x8*)&As[row * 264 + col];
            if (col < 128) *(bf16x8*)(U + (size_t)grow * JDIM + col) = v;
            else           *(bf16x8*)(V + (size_t)grow * JDIM + (col - 128)) = v;
        }
    }
}

// ---------------------------------------------------------------------------
// Kernel 2 (FUSED gather + final): per 64-row block:
//   phase A: E1[r] = relu(mean_s relu(U[idx0[s,r]] + V[idx1[s,r]] + bg))
//            computed straight into LDS (E1 never touches HBM).
//   phase B: E2 = relu(U + E1 @ Wg_bot + bg); out = E2 @ Wf + bf  (MFMA K=128)
// Gather keeps k_gather's coalescing (16-lane group reads one 256B row) with
// 2x its per-thread MLP (32 loads in flight). B panel register-resident.
// ---------------------------------------------------------------------------
__global__ __launch_bounds__(256) void k_gfinal(
    const __bf16* __restrict__ U, const __bf16* __restrict__ V,
    const __bf16* __restrict__ WtGv, const float* __restrict__ bg,
    const float* __restrict__ Wf, const float* __restrict__ bf,
    const int* __restrict__ idx0, const int* __restrict__ idx1,
    float* __restrict__ out)
{
    __shared__ int    sidx0[8][64], sidx1[8][64];   // 4 KB
    __shared__ __bf16 E1s[64 * 136];                // 17.4 KB
    __shared__ __bf16 Us [64 * 136];                // 17.4 KB
    __shared__ float  part[4][64][2];               // 2 KB

    const int tid  = threadIdx.x;
    const int row0 = blockIdx.x * 64;
    const int wave = tid >> 6, lane = tid & 63;
    const int lm = lane & 15, lq = lane >> 4;

    // B panel resident: 8 frags = 32 VGPR
    bf16x8 b3[2][4];
    #pragma unroll
    for (int nt = 0; nt < 2; ++nt) {
        int ntg = wave * 2 + nt;
        #pragma unroll
        for (int ks = 0; ks < 4; ++ks)
            b3[nt][ks] = *(const bf16x8*)(WtGv + (size_t)(ntg * 16 + lm) * 128 + ks * 32 + lq * 8);
    }

    // stage indices (1024 ints, 4/thread) and U tile (4 bf16x8/thread)
    #pragma unroll
    for (int it = 0; it < 4; ++it) {
        int fid = it * 256 + tid;                 // 0..1023
        int m = fid >> 9, rem = fid & 511;
        int s = rem >> 6, il = rem & 63;
        int gr = row0 + il; if (gr >= L_NODES) gr = L_NODES - 1;
        int val = (m ? idx1 : idx0)[(size_t)s * L_NODES + gr];
        if (m) sidx1[s][il] = val; else sidx0[s][il] = val;
    }
    #pragma unroll
    for (int it = 0; it < 4; ++it) {
        int fid = it * 256 + tid;                 // 0..1023
        int r = fid >> 4, c8 = fid & 15;
        int g = row0 + r; if (g >= L_NODES) g = L_NODES - 1;
        *(bf16x8*)&Us[r * 136 + c8 * 8] = *(const bf16x8*)(U + (size_t)g * JDIM + c8 * 8);
    }
    __syncthreads();

    // ---- phase A: gather-add into E1s ----
    {
        const int c0 = (tid & 15) * 8;            // col chunk
        const int rb = tid >> 4;                  // row base 0..15 (+16k)
        float bias[8];
        *(float4*)&bias[0] = *(const float4*)(bg + c0);
        *(float4*)&bias[4] = *(const float4*)(bg + c0 + 4);

        float acc[4][8] = {};
        #pragma unroll
        for (int s = 0; s < 8; ++s) {
            #pragma unroll
            for (int rr = 0; rr < 4; ++rr) {
                int r = rb + rr * 16;
                int a0 = sidx0[s][r], a1 = sidx1[s][r];
                bf16x8 u = *(const bf16x8*)(U + (size_t)a0 * JDIM + c0);
                bf16x8 v = *(const bf16x8*)(V + (size_t)a1 * JDIM + c0);
                #pragma unroll
                for (int p = 0; p < 8; ++p)
                    acc[rr][p] += fmaxf((float)u[p] + (float)v[p] + bias[p], 0.f);
            }
        }
        #pragma unroll
        for (int rr = 0; rr < 4; ++rr) {
            int r = rb + rr * 16;
            bf16x8 o;
            #pragma unroll
            for (int p = 0; p < 8; ++p)
                o[p] = (__bf16)fmaxf(acc[rr][p] * 0.125f, 0.f);
            *(bf16x8*)&E1s[r * 136 + c0] = o;
        }
    }
    __syncthreads();

    // ---- phase B: E2 = relu(U + E1 @ Wg_bot + bg); head ----
    floatx4 acc[4][2] = {};
    #pragma unroll
    for (int ks = 0; ks < 4; ++ks) {
        bf16x8 af[4];
        #pragma unroll
        for (int t = 0; t < 4; ++t)
            af[t] = *(const bf16x8*)&E1s[(t * 16 + lm) * 136 + ks * 32 + lq * 8];
        #pragma unroll
        for (int t = 0; t < 4; ++t)
            #pragma unroll
            for (int nt = 0; nt < 2; ++nt)
                acc[t][nt] = __builtin_amdgcn_mfma_f32_16x16x32_bf16(
                    af[t], b3[nt][ks], acc[t][nt], 0, 0, 0);
    }

    float bias[2], wf0[2], wf1[2];
    #pragma unroll
    for (int nt = 0; nt < 2; ++nt) {
        int col = (wave * 2 + nt) * 16 + lm;
        bias[nt] = bg[col];
        wf0[nt] = Wf[col * 2 + 0];
        wf1[nt] = Wf[col * 2 + 1];
    }
    #pragma unroll
    for (int t = 0; t < 4; ++t) {
        float p0[4], p1[4];
        #pragma unroll
        for (int p = 0; p < 4; ++p) {
            int r = t * 16 + lq * 4 + p;
            float a0 = 0.f, a1 = 0.f;
            #pragma unroll
            for (int nt = 0; nt < 2; ++nt) {
                int col = (wave * 2 + nt) * 16 + lm;
                float e2 = fmaxf((float)Us[r * 136 + col] + acc[t][nt][p] + bias[nt], 0.f);
                a0 = fmaf(e2, wf0[nt], a0);
                a1 = fmaf(e2, wf1[nt], a1);
            }
            p0[p] = a0; p1[p] = a1;
        }
        #pragma unroll
        for (int m = 1; m <= 8; m <<= 1)
            #pragma unroll
            for (int p = 0; p < 4; ++p) {
                p0[p] += __shfl_xor(p0[p], m, 16);
                p1[p] += __shfl_xor(p1[p], m, 16);
            }
        if (lm == 0)
            #pragma unroll
            for (int p = 0; p < 4; ++p) {
                part[wave][t * 16 + lq * 4 + p][0] = p0[p];
                part[wave][t * 16 + lq * 4 + p][1] = p1[p];
            }
    }
    __syncthreads();

    if (tid < 128) {
        int row = tid >> 1, o = tid & 1;
        int grow = row0 + row;
        if (grow < L_NODES)
            out[(size_t)grow * 2 + o] =
                part[0][row][o] + part[1][row][o] + part[2][row][o] + part[3][row][o] + bf[o];
    }
}

// ---------------------------------------------------------------------------
extern "C" void kernel_launch(void* const* d_in, const int* in_sizes, int n_in,
                              void* d_out, int out_size, void* d_ws, size_t ws_size,
                              hipStream_t stream) {
    const float* X    = (const float*)d_in[0];
    const float* W_h1 = (const float*)d_in[1];
    const float* b_h1 = (const float*)d_in[2];
    const float* W_g1 = (const float*)d_in[3];
    const float* b_g1 = (const float*)d_in[4];
    const float* W_f  = (const float*)d_in[5];
    const float* b_f  = (const float*)d_in[6];
    const int*   idx0 = (const int*)d_in[7];
    const int*   idx1 = (const int*)d_in[8];
    float* out = (float*)d_out;

    __bf16* U    = (__bf16*)d_ws;                         // 25.6 MB
    __bf16* V    = U   + (size_t)L_NODES * JDIM;          // 25.6 MB
    __bf16* WtH  = V   + (size_t)L_NODES * JDIM;          // 64 KB
    __bf16* WtG2 = WtH + 32768;                           // 64 KB
    __bf16* WtGv = WtG2 + 128 * 128;                      // alias: rows 128.. of WtG2

    k_prep<<<128, 256, 0, stream>>>(W_h1, W_g1, WtH, WtG2);
    k_h1uv<<<(L_NODES + 63) / 64, 256, 0, stream>>>(X, WtH, WtG2, b_h1, U, V);
    k_gfinal<<<(L_NODES + 63) / 64, 256, 0, stream>>>(U, V, WtGv, b_g1, W_f, b_f,
                                                      idx0, idx1, out);
}